// Round 6
// baseline (86.955 us; speedup 1.0000x reference)
//
#include <hip/hip_runtime.h>
#include <hip/hip_bf16.h>

// Problem constants
#define BATCH 32768
#define NIN   256
#define NOUT  256
// degrees 1..8 via MFMA; degree 0 (T_0 = 1) folded into per-column bias

typedef __attribute__((ext_vector_type(8))) short bf16x8;
typedef __attribute__((ext_vector_type(4))) float f32x4;
typedef __attribute__((ext_vector_type(2))) float f32x2;

static __device__ __forceinline__ unsigned short bf16_rne(float f) {
  unsigned u = __float_as_uint(f);
  u += 0x7fffu + ((u >> 16) & 1u);
  return (unsigned short)(u >> 16);
}

// fast tanh: t = sign(v) * (1 - z) / (1 + z), z = exp(-2|v|)
static __device__ __forceinline__ float fast_tanh(float v) {
  float a = fabsf(v);
  float z = __expf(-2.0f * a);
  float r = (1.0f - z) * __builtin_amdgcn_rcpf(1.0f + z);
  return copysignf(r, v);
}

static __device__ __forceinline__ unsigned pack_pair(f32x2 v) {
  __hip_bfloat162 h2 = __float22bfloat162_rn(make_float2(v[0], v[1]));
  union { __hip_bfloat162 h; unsigned u; } cv;
  cv.h = h2;
  return cv.u;
}

static __device__ __forceinline__ void init_state(const f32x4 x0, const f32x4 x1,
                                                  f32x2* cur, f32x2* prev,
                                                  f32x2* t2) {
  #pragma unroll
  for (int p = 0; p < 4; ++p) {
    float va = (p < 2) ? x0[2 * p]     : x1[2 * p - 4];
    float vb = (p < 2) ? x0[2 * p + 1] : x1[2 * p - 3];
    float ta = fast_tanh(va);
    float tb = fast_tanh(vb);
    cur[p]  = (f32x2){ta, tb};        // T_1
    t2[p]   = cur[p] + cur[p];
    prev[p] = (f32x2){1.0f, 1.0f};    // T_0
  }
}

// async global->LDS, 16B per lane, LDS dest = uniform base + lane*16
static __device__ __forceinline__ void gload_lds16(const void* g, void* l) {
  __builtin_amdgcn_global_load_lds(
      (const __attribute__((address_space(1))) unsigned int*)g,
      (__attribute__((address_space(3))) unsigned int*)l, 16, 0, 0);
}

// ---------------------------------------------------------------------------
// Prepack: Bp[(((cbk*8+ic)*16 + (dm*2+nt))*512) + kg*128 + col*8 + j] =
//          bf16( c_basis[n][i][dm+1] * c_act[n][i] )
//   n = cbk*32 + nt*16 + col,  i = ic*32 + kg*8 + j.
// Per (cbk, ic): 16 contiguous 1KB fragments (d-major) = 16KB, in exactly
// the order cheby_mfma stages them into LDS. 2^19 = 524288 elements.
// ---------------------------------------------------------------------------
__global__ void cheby_prepack(const float* __restrict__ cb,
                              const float* __restrict__ ca,
                              unsigned short* __restrict__ Bp) {
  int tid = blockIdx.x * 256 + threadIdx.x;
  int j    = tid & 7;
  int col  = (tid >> 3) & 15;
  int kg   = (tid >> 7) & 3;
  int nt   = (tid >> 9) & 1;
  int dm   = (tid >> 10) & 7;     // d-1
  int ic   = (tid >> 13) & 7;
  int cbk  = (tid >> 16) & 7;
  int i = ic * 32 + kg * 8 + j;
  int n = cbk * 32 + nt * 16 + col;
  float w = cb[n * (NIN * 9) + i * 9 + (dm + 1)] * ca[n * NIN + i];
  Bp[tid] = bf16_rne(w);
}

// bias[n] = sum_i c_basis[n][i][0] * c_act[n][i]   (T_0 == 1 term)
__global__ void cheby_bias(const float* __restrict__ cb,
                           const float* __restrict__ ca,
                           float* __restrict__ bias) {
  int n = blockIdx.x;
  int l = threadIdx.x;            // 64 threads = one wave
  float s = 0.0f;
  #pragma unroll
  for (int k = 0; k < 4; ++k) {
    int i = l + k * 64;
    s += cb[n * (NIN * 9) + i * 9] * ca[n * NIN + i];
  }
  #pragma unroll
  for (int off = 32; off; off >>= 1) s += __shfl_down(s, off);
  if (l == 0) bias[n] = s;
}

// ---------------------------------------------------------------------------
// Fused cheby + GEMM: A in registers, B in LDS.
// Grid: 2048 blocks (rb = bid>>3 row-block of 128, cbk = bid&7 col-block
// of 32). Block: 4 waves stacked by rows; wave = 32 rows x 32 cols
// (2mt x 2nt of 16x16x32). Rows disjoint across waves -> tanh/recurrence
// computed exactly once per x element, A-frags built in registers.
// B (16KB per ic) staged into LDS with global_load_lds (width 16),
// double-buffered, shared by all 4 waves. 16 waves/CU target.
// ---------------------------------------------------------------------------
__global__ __launch_bounds__(256, 4)
void cheby_mfma(const float* __restrict__ x,
                const unsigned short* __restrict__ Bp,
                const float* __restrict__ bias,
                float* __restrict__ out) {
  __shared__ unsigned short Bl[2][16][512];   // 2 x 16KB

  int tid  = threadIdx.x;
  int w    = tid >> 6;
  int lane = tid & 63;
  int row16 = lane & 15;          // A row / B col / C-D col
  int kg    = lane >> 4;          // k-group 0..3

  int rb  = blockIdx.x >> 3;
  int cbk = blockIdx.x & 7;

  // x pointers: wave w owns rows rb*128 + w*32 .. +31 (mt 0/1 add 16)
  const float* xw = x + (size_t)(rb * 128 + w * 32 + row16) * NIN + kg * 8;

  // B staging: wave w stages fragments 4w..4w+3 of the 16KB (cbk, ic) chunk
  const char* bsrc = (const char*)Bp +
                     ((size_t)cbk * 8) * 16384 + w * 4096 + lane * 16;
  char* lwr = (char*)Bl + w * 4096;
  // B read: per (d, nt) fragment at kg*256 + row16*16
  const char* lrd = (const char*)Bl + kg * 256 + row16 * 16;

  f32x4 acc[2][2];
  #pragma unroll
  for (int a = 0; a < 2; ++a)
    #pragma unroll
    for (int b = 0; b < 2; ++b) acc[a][b] = (f32x4)0.0f;

  // ---- prologue: stage B(ic=0) into buf0, load x(ic=0) ----
  #pragma unroll
  for (int q = 0; q < 4; ++q)
    gload_lds16(bsrc + q * 1024, lwr + q * 1024);
  f32x4 xa[2], xb[2];
  #pragma unroll
  for (int mt = 0; mt < 2; ++mt) {
    const float* p = xw + (size_t)mt * (16 * NIN);
    xa[mt] = *(const f32x4*)p;
    xb[mt] = *(const f32x4*)(p + 4);
  }
  __syncthreads();   // vmcnt(0) drain by compiler -> B(0) ready

  f32x2 cur[2][4], prev[2][4], t2[2][4];

  for (int ic = 0; ic < 8; ++ic) {
    int buf = ic & 1;
    #pragma unroll
    for (int mt = 0; mt < 2; ++mt)
      init_state(xa[mt], xb[mt], cur[mt], prev[mt], t2[mt]);

    if (ic < 7) {
      // stage B(ic+1) into the other buffer; load x(ic+1)
      const char* bs = bsrc + (size_t)(ic + 1) * 16384;
      char* lw = lwr + (buf ^ 1) * 16384;
      #pragma unroll
      for (int q = 0; q < 4; ++q)
        gload_lds16(bs + q * 1024, lw + q * 1024);
      #pragma unroll
      for (int mt = 0; mt < 2; ++mt) {
        const float* p = xw + (size_t)mt * (16 * NIN) + (ic + 1) * 32;
        xa[mt] = *(const f32x4*)p;
        xb[mt] = *(const f32x4*)(p + 4);
      }
    }

    const char* lr = lrd + buf * 16384;
    #pragma unroll
    for (int d = 1; d <= 8; ++d) {
      bf16x8 bfr[2];
      #pragma unroll
      for (int nt = 0; nt < 2; ++nt)
        bfr[nt] = *(const bf16x8*)(lr + ((d - 1) * 2 + nt) * 1024);
      bf16x8 af[2];
      #pragma unroll
      for (int mt = 0; mt < 2; ++mt) {
        union { unsigned u[4]; bf16x8 v; } au;
        #pragma unroll
        for (int p = 0; p < 4; ++p) au.u[p] = pack_pair(cur[mt][p]);
        af[mt] = au.v;
      }
      #pragma unroll
      for (int mt = 0; mt < 2; ++mt)
        #pragma unroll
        for (int nt = 0; nt < 2; ++nt)
          acc[mt][nt] = __builtin_amdgcn_mfma_f32_16x16x32_bf16(
              af[mt], bfr[nt], acc[mt][nt], 0, 0, 0);
      if (d < 8) {   // T_{d+1} = 2t*T_d - T_{d-1}  (v_pk_fma_f32)
        #pragma unroll
        for (int mt = 0; mt < 2; ++mt)
          #pragma unroll
          for (int p = 0; p < 4; ++p) {
            f32x2 nx = __builtin_elementwise_fma(t2[mt][p], cur[mt][p],
                                                 -prev[mt][p]);
            prev[mt][p] = cur[mt][p];
            cur[mt][p]  = nx;
          }
      }
    }
    if (ic < 7) __syncthreads();
  }

  // epilogue: C/D layout col = lane&15, row = (lane>>4)*4 + q  (m89/m91)
  #pragma unroll
  for (int nt = 0; nt < 2; ++nt) {
    int c = cbk * 32 + nt * 16 + row16;
    float bv = bias[c];
    #pragma unroll
    for (int mt = 0; mt < 2; ++mt) {
      int r0 = rb * 128 + w * 32 + mt * 16 + kg * 4;
      #pragma unroll
      for (int q = 0; q < 4; ++q)
        out[(size_t)(r0 + q) * NOUT + c] = acc[mt][nt][q] + bv;
    }
  }
}

extern "C" void kernel_launch(void* const* d_in, const int* in_sizes, int n_in,
                              void* d_out, int out_size, void* d_ws, size_t ws_size,
                              hipStream_t stream) {
  const float* x  = (const float*)d_in[0];
  const float* cb = (const float*)d_in[1];   // c_basis (256,256,9)
  const float* ca = (const float*)d_in[2];   // c_act   (256,256)
  float* out = (float*)d_out;

  unsigned short* Bp = (unsigned short*)d_ws;                    // 1 MB
  float* bias = (float*)((char*)d_ws + 8 * NIN * NOUT * 2);      // 1 KB

  cheby_prepack<<<(8 * NIN * NOUT) / 256, 256, 0, stream>>>(cb, ca, Bp);
  cheby_bias<<<NOUT, 64, 0, stream>>>(cb, ca, bias);
  cheby_mfma<<<2048, 256, 0, stream>>>(x, Bp, bias, out);
}

// Round 7
// 50.360 us; speedup vs baseline: 1.7267x; 1.7267x over previous
//
#include <hip/hip_runtime.h>
#include <hip/hip_bf16.h>

// Problem constants
#define BATCH 32768
#define NIN   256
#define NOUT  256
// degrees 1..8 via MFMA; degree 0 (T_0 = 1) folded into per-column bias

typedef __attribute__((ext_vector_type(8))) short bf16x8;
typedef __attribute__((ext_vector_type(4))) float f32x4;
typedef __attribute__((ext_vector_type(2))) float f32x2;
typedef __attribute__((ext_vector_type(4))) unsigned int u32x4;

static __device__ __forceinline__ unsigned short bf16_rne(float f) {
  unsigned u = __float_as_uint(f);
  u += 0x7fffu + ((u >> 16) & 1u);
  return (unsigned short)(u >> 16);
}

// fast tanh: t = sign(v) * (1 - z) / (1 + z), z = exp(-2|v|)
static __device__ __forceinline__ float fast_tanh(float v) {
  float a = fabsf(v);
  float z = __expf(-2.0f * a);
  float r = (1.0f - z) * __builtin_amdgcn_rcpf(1.0f + z);
  return copysignf(r, v);
}

static __device__ __forceinline__ unsigned pack_pair(f32x2 v) {
  __hip_bfloat162 h2 = __float22bfloat162_rn(make_float2(v[0], v[1]));
  union { __hip_bfloat162 h; unsigned u; } cv;
  cv.h = h2;
  return cv.u;
}

static __device__ __forceinline__ void init_state(const f32x4 x0, const f32x4 x1,
                                                  f32x2* cur, f32x2* prev,
                                                  f32x2* t2) {
  #pragma unroll
  for (int p = 0; p < 4; ++p) {
    float va = (p < 2) ? x0[2 * p]     : x1[2 * p - 4];
    float vb = (p < 2) ? x0[2 * p + 1] : x1[2 * p - 3];
    float ta = fast_tanh(va);
    float tb = fast_tanh(vb);
    cur[p]  = (f32x2){ta, tb};        // T_1
    t2[p]   = cur[p] + cur[p];
    prev[p] = (f32x2){1.0f, 1.0f};    // T_0
  }
}

// Barrier that does NOT drain vmcnt (T4): cross-wave correctness here only
// needs the LDS writes visible (lgkmcnt). x-prefetch / B global loads stay
// in flight across the barrier. sched_barrier fences code motion (rule #18).
static __device__ __forceinline__ void pipeline_barrier() {
  __builtin_amdgcn_sched_barrier(0);
  asm volatile("s_waitcnt lgkmcnt(0)" ::: "memory");
  __builtin_amdgcn_s_barrier();
  __builtin_amdgcn_sched_barrier(0);
}

// ---------------------------------------------------------------------------
// Prepack: Bp[((dm*8+ic)*16+tile)*512 + kg*128 + col*8 + j] =
//          bf16( c_basis[n][i][dm+1] * c_act[n][i] )
//   with i = ic*32 + kg*8 + j,  n = tile*16 + col.
// ---------------------------------------------------------------------------
__global__ void cheby_prepack(const float* __restrict__ cb,
                              const float* __restrict__ ca,
                              unsigned short* __restrict__ Bp) {
  int tid = blockIdx.x * 256 + threadIdx.x;
  int j    = tid & 7;
  int col  = (tid >> 3) & 15;
  int kg   = (tid >> 7) & 3;
  int tile = (tid >> 9) & 15;
  int ic   = (tid >> 13) & 7;
  int dm   = tid >> 16;           // d-1, 0..7
  int i = ic * 32 + kg * 8 + j;
  int n = tile * 16 + col;
  float w = cb[n * (NIN * 9) + i * 9 + (dm + 1)] * ca[n * NIN + i];
  Bp[tid] = bf16_rne(w);
}

// bias[n] = sum_i c_basis[n][i][0] * c_act[n][i]   (T_0 == 1 term)
__global__ void cheby_bias(const float* __restrict__ cb,
                           const float* __restrict__ ca,
                           float* __restrict__ bias) {
  int n = blockIdx.x;
  int l = threadIdx.x;            // 64 threads = one wave
  float s = 0.0f;
  #pragma unroll
  for (int k = 0; k < 4; ++k) {
    int i = l + k * 64;
    s += cb[n * (NIN * 9) + i * 9] * ca[n * NIN + i];
  }
  #pragma unroll
  for (int off = 32; off; off >>= 1) s += __shfl_down(s, off);
  if (l == 0) bias[n] = s;
}

// ---------------------------------------------------------------------------
// Fused cheby + GEMM, software-pipelined LDS-staged A (R5 skeleton).
// Grid: 512 blocks x 256 threads (4 waves). Block tile: 64 rows x 256 cols
// (block spans ALL cols -> tanh/recurrence once per x element globally).
// Iteration ic: MFMA on buf interleaved with compute+pack of ic+1 into
// buf^1; ONE lgkm-only barrier per ic (vmem never drained at barriers).
// Writer: wave w owns plane mt=w at lane*16 -> conflict-free ds_write_b128.
// ---------------------------------------------------------------------------
__global__ __launch_bounds__(256, 2)
void cheby_mfma(const float* __restrict__ x,
                const unsigned short* __restrict__ Bp,
                const float* __restrict__ bias,
                float* __restrict__ out) {
  // [buf][d-1][mt][frag: kg*256B + row16*16B]  -- 1KB fragments, 64KB total
  __shared__ unsigned short Asm[2][8][4][512];

  int tid  = threadIdx.x;
  int w    = tid >> 6;
  int lane = tid & 63;
  int row16 = lane & 15;          // A row / B col / C-D col
  int kg    = lane >> 4;          // k-group 0..3

  int base_row = blockIdx.x * 64;
  int tile0    = w * 4;           // wave's 4 column tiles (64 cols)

  // writer role: wave w covers rows w*16..w*16+15 (plane mt=w)
  const float* xw = x + (size_t)(base_row + w * 16 + row16) * NIN + kg * 8;
  char* wbase = (char*)Asm + (w * 1024 + lane * 16);
  // reader
  const char* abase   = (const char*)Asm + lane * 16;
  const char* bp_lane = (const char*)Bp + kg * 256 + row16 * 16;

  f32x4 acc[4][4];
  #pragma unroll
  for (int a = 0; a < 4; ++a)
    #pragma unroll
    for (int b = 0; b < 4; ++b) acc[a][b] = (f32x4)0.0f;

  // ---- prologue: compute + write buf0 for ic=0 ----
  f32x4 xa = *(const f32x4*)xw;
  f32x4 xb = *(const f32x4*)(xw + 4);
  {
    f32x2 cur[4], prev[4], t2[4];
    init_state(xa, xb, cur, prev, t2);
    #pragma unroll
    for (int d = 1; d <= 8; ++d) {
      u32x4 pk;
      #pragma unroll
      for (int p = 0; p < 4; ++p) pk[p] = pack_pair(cur[p]);
      *(u32x4*)(wbase + (d - 1) * 4096) = pk;
      if (d < 8) {
        #pragma unroll
        for (int p = 0; p < 4; ++p) {
          f32x2 nx = __builtin_elementwise_fma(t2[p], cur[p], -prev[p]);
          prev[p] = cur[p];
          cur[p]  = nx;
        }
      }
    }
  }
  // x for ic=1 (consumed at top of iteration 0)
  xa = *(const f32x4*)(xw + 32);
  xb = *(const f32x4*)(xw + 36);
  pipeline_barrier();

  // ---- main loop: MFMA(ic) || compute+write(ic+1) ----
  for (int ic = 0; ic < 7; ++ic) {
    int buf = ic & 1;
    f32x2 cur[4], prev[4], t2[4];
    init_state(xa, xb, cur, prev, t2);            // state for ic+1
    if (ic < 6) {                                 // prefetch x for ic+2
      xa = *(const f32x4*)(xw + (ic + 2) * 32);
      xb = *(const f32x4*)(xw + (ic + 2) * 32 + 4);
    }
    const char* ai  = abase + buf * 32768;
    char*       wp  = wbase + (buf ^ 1) * 32768;
    const char* bpi = bp_lane + (size_t)(ic * 16 + tile0) * 1024;

    #pragma unroll
    for (int d = 1; d <= 8; ++d) {
      bf16x8 af[4], bfr[4];
      #pragma unroll
      for (int mt = 0; mt < 4; ++mt)
        af[mt] = *(const bf16x8*)(ai + (d - 1) * 4096 + mt * 1024);
      #pragma unroll
      for (int nt = 0; nt < 4; ++nt)
        bfr[nt] = *(const bf16x8*)(bpi + (size_t)(d - 1) * 131072 + nt * 1024);
      // pack + write degree d of NEXT ic (issues under the MFMAs below)
      u32x4 pk;
      #pragma unroll
      for (int p = 0; p < 4; ++p) pk[p] = pack_pair(cur[p]);
      *(u32x4*)(wp + (d - 1) * 4096) = pk;
      if (d < 8) {   // T_{d+1} = 2t*T_d - T_{d-1}  (v_pk_fma_f32)
        #pragma unroll
        for (int p = 0; p < 4; ++p) {
          f32x2 nx = __builtin_elementwise_fma(t2[p], cur[p], -prev[p]);
          prev[p] = cur[p];
          cur[p]  = nx;
        }
      }
      __builtin_amdgcn_s_setprio(1);
      #pragma unroll
      for (int mt = 0; mt < 4; ++mt)
        #pragma unroll
        for (int nt = 0; nt < 4; ++nt)
          acc[mt][nt] = __builtin_amdgcn_mfma_f32_16x16x32_bf16(
              af[mt], bfr[nt], acc[mt][nt], 0, 0, 0);
      __builtin_amdgcn_s_setprio(0);
    }
    pipeline_barrier();
  }

  // ---- final iteration ic=7: MFMA only (buf=1) ----
  {
    const char* ai  = abase + 32768;
    const char* bpi = bp_lane + (size_t)(7 * 16 + tile0) * 1024;
    #pragma unroll
    for (int d = 1; d <= 8; ++d) {
      bf16x8 af[4], bfr[4];
      #pragma unroll
      for (int mt = 0; mt < 4; ++mt)
        af[mt] = *(const bf16x8*)(ai + (d - 1) * 4096 + mt * 1024);
      #pragma unroll
      for (int nt = 0; nt < 4; ++nt)
        bfr[nt] = *(const bf16x8*)(bpi + (size_t)(d - 1) * 131072 + nt * 1024);
      __builtin_amdgcn_s_setprio(1);
      #pragma unroll
      for (int mt = 0; mt < 4; ++mt)
        #pragma unroll
        for (int nt = 0; nt < 4; ++nt)
          acc[mt][nt] = __builtin_amdgcn_mfma_f32_16x16x32_bf16(
              af[mt], bfr[nt], acc[mt][nt], 0, 0, 0);
      __builtin_amdgcn_s_setprio(0);
    }
  }

  // epilogue: C/D layout col = lane&15, row = (lane>>4)*4 + q  (m89/m91)
  #pragma unroll
  for (int nt = 0; nt < 4; ++nt) {
    int c = (tile0 + nt) * 16 + row16;
    float bv = bias[c];
    #pragma unroll
    for (int mt = 0; mt < 4; ++mt) {
      int r0 = base_row + mt * 16 + kg * 4;
      #pragma unroll
      for (int q = 0; q < 4; ++q)
        out[(size_t)(r0 + q) * NOUT + c] = acc[mt][nt][q] + bv;
    }
  }
}

extern "C" void kernel_launch(void* const* d_in, const int* in_sizes, int n_in,
                              void* d_out, int out_size, void* d_ws, size_t ws_size,
                              hipStream_t stream) {
  const float* x  = (const float*)d_in[0];
  const float* cb = (const float*)d_in[1];   // c_basis (256,256,9)
  const float* ca = (const float*)d_in[2];   // c_act   (256,256)
  float* out = (float*)d_out;

  unsigned short* Bp = (unsigned short*)d_ws;                    // 1 MB
  float* bias = (float*)((char*)d_ws + 8 * NIN * NOUT * 2);      // 1 KB

  cheby_prepack<<<(8 * NIN * NOUT) / 256, 256, 0, stream>>>(cb, ca, Bp);
  cheby_bias<<<NOUT, 64, 0, stream>>>(cb, ca, bias);
  cheby_mfma<<<512, 256, 0, stream>>>(x, Bp, bias, out);
}